// Round 16
// baseline (125.010 us; speedup 1.0000x reference)
//
#include <hip/hip_runtime.h>

#define BS 16
#define S  256
#define H  1024
#define T  32

// ws layout (floats): ps[512] | p1[4096*32] | p2[4096*32] | cnt[16 uint]
#define PS_OFF  0
#define P1_OFF  512
#define P2_OFF  (P1_OFF + BS * S * T)          // 131584
#define CNT_OFF (P2_OFF + BS * S * T)          // 262656 (float idx)
#define TARGET  24u                            // 16 gemm + 8 ps blocks per batch

typedef __bf16 bf16x8 __attribute__((ext_vector_type(8)));
typedef float  f32x4  __attribute__((ext_vector_type(4)));

__device__ inline bf16x8 to_bf8(float4 lo, float4 hi) {
    bf16x8 r;
    r[0] = (__bf16)lo.x; r[1] = (__bf16)lo.y; r[2] = (__bf16)lo.z; r[3] = (__bf16)lo.w;
    r[4] = (__bf16)hi.x; r[5] = (__bf16)hi.y; r[6] = (__bf16)hi.z; r[7] = (__bf16)hi.w;
    return r;
}

// ---------------------------------------------------------------------------
// Single dispatch, 1024 blocks x 256 thr, ALL CO-RESIDENT (4 blocks/CU:
// launch_bounds(256,4) caps VGPR<=128; LDS 33KB -> 4/CU) => producer/consumer
// flags cannot deadlock regardless of dispatch order.
//   blk<256   : GEMM m-tile (16 rows, full K=1024; wave wv = cols 16wv..+16,
//               4 k-chunks x 8 MFMAs, 2 acc chains). Signal cnt[batch].
//   256..383  : ps (R10 wave-parallel body). Signal cnt[batch].
//   ALL blocks: wait cnt[b]==24 (acquire), then stream 4 output rows:
//               out[row,j,t] = p1[row,t]+ps[b,t] + p2[b,j,t].
// R15 failed ONLY because the flag-re-arm memset used a byte offset on a
// float* (flags never zeroed -> consumers never waited). Fixed below.
// ---------------------------------------------------------------------------
__global__ __launch_bounds__(256, 4) void fused(
    const float* __restrict__ seq, const float* __restrict__ E,
    const float* __restrict__ W, const float* __restrict__ bias,
    float* __restrict__ ws, float* __restrict__ out)
{
    const int tid = threadIdx.x;
    const int lane = tid & 63, wv = tid >> 6;
    const int blk = blockIdx.x;
    unsigned* cnt = (unsigned*)(ws + CNT_OFF);

    __shared__ __align__(16) __bf16 Ebf[16][1032];    // 33 KB (gemm blocks only)

    if (blk < 256) {
        // ================= producer: GEMM m-tile =================
        const int m0 = blk * 16;
        // stage 16x1024 f32 -> bf16 LDS, two halves (coalesced 32B/lane)
        #pragma unroll
        for (int h = 0; h < 2; ++h) {
            float4 ta[4], tb[4];
            #pragma unroll
            for (int i = 0; i < 4; ++i) {
                int c = tid + i * 256;                // 0..1023
                int row = c >> 6, c8 = c & 63;
                const float4* src = (const float4*)(E + (size_t)(m0 + row) * H
                                                    + h * 512 + c8 * 8);
                ta[i] = src[0]; tb[i] = src[1];
            }
            #pragma unroll
            for (int i = 0; i < 4; ++i) {
                int c = tid + i * 256;
                int row = c >> 6, c8 = c & 63;
                *(bf16x8*)&Ebf[row][h * 512 + c8 * 8] = to_bf8(ta[i], tb[i]);
            }
        }
        __syncthreads();

        // wave wv: cols [16wv,16wv+16), full K in 4 chunks of 256
        const int col = wv * 16 + (lane & 15);
        const int ksub = (lane >> 4) * 8;
        const float* wbase = W + (size_t)(col & 31) * (3 * H)
                               + ((col >= 32) ? H : 0) + ksub;
        const int erow = lane & 15;
        f32x4 accA = {0.f,0.f,0.f,0.f}, accB = {0.f,0.f,0.f,0.f};
        #pragma unroll
        for (int ch = 0; ch < 4; ++ch) {
            bf16x8 bf[8];
            #pragma unroll
            for (int s = 0; s < 8; ++s)
                bf[s] = to_bf8(*(const float4*)(wbase + ch * 256 + s * 32),
                               *(const float4*)(wbase + ch * 256 + s * 32 + 4));
            #pragma unroll
            for (int s = 0; s < 8; s += 2) {
                bf16x8 a0 = *(const bf16x8*)&Ebf[erow][ch * 256 + s * 32 + ksub];
                bf16x8 a1 = *(const bf16x8*)&Ebf[erow][ch * 256 + (s+1) * 32 + ksub];
                accA = __builtin_amdgcn_mfma_f32_16x16x32_bf16(a0, bf[s],   accA, 0, 0, 0);
                accB = __builtin_amdgcn_mfma_f32_16x16x32_bf16(a1, bf[s+1], accB, 0, 0, 0);
            }
        }
        f32x4 acc = accA + accB;

        // store: D layout col=lane&15, row=(lane>>4)*4+r; dst wave-uniform
        const int orow = (lane >> 4) * 4;
        float* dst = (wv < 2) ? (ws + P1_OFF) : (ws + P2_OFF);
        const int c = col & 31;
        #pragma unroll
        for (int r = 0; r < 4; ++r)
            dst[(size_t)(m0 + orow + r) * T + c] = acc[r];

        __syncthreads();                              // all stores issued
        if (tid == 0) {
            __threadfence();                          // device-scope release
            __hip_atomic_fetch_add(&cnt[blk >> 4], 1u,
                                   __ATOMIC_RELEASE, __HIP_MEMORY_SCOPE_AGENT);
        }
    } else if (blk < 384) {
        // ================= producer: ps (R10 body) =================
        float* ps = ws + PS_OFF;
        const int o = (blk - 256) * 4 + wv;           // 0..511, batch=(blk-256)>>3
        const int bb = o >> 5, t = o & 31;
        const float4* sp = (const float4*)(seq + (size_t)bb * H) + lane * 4;
        const float4* wp = (const float4*)(W + (size_t)t * (3 * H) + 2 * H) + lane * 4;
        float acc = 0.f;
        #pragma unroll
        for (int k = 0; k < 4; ++k) {
            float4 a = sp[k], w = wp[k];
            acc += a.x * w.x + a.y * w.y + a.z * w.z + a.w * w.w;
        }
        #pragma unroll
        for (int m = 32; m >= 1; m >>= 1) acc += __shfl_xor(acc, m);
        if (lane == 0) ps[o] = acc + bias[t];
        __syncthreads();
        if (tid == 0) {
            __threadfence();
            __hip_atomic_fetch_add(&cnt[(blk - 256) >> 3], 1u,
                                   __ATOMIC_RELEASE, __HIP_MEMORY_SCOPE_AGENT);
        }
    }

    // ================= consumer: 4 output rows per block =================
    const int r0 = blk * 4;                           // rows r0..r0+3 (same batch)
    const int b = blk >> 6;

    if (tid == 0) {
        while (__hip_atomic_load(&cnt[b], __ATOMIC_ACQUIRE,
                                 __HIP_MEMORY_SCOPE_AGENT) < TARGET)
            __builtin_amdgcn_s_sleep(8);
    }
    __syncthreads();                                  // flag seen -> all proceed

    const float4* p2v = (const float4*)(ws + P2_OFF) + (size_t)b * (S * T / 4);
    const float4 psv = *(const float4*)((ws + PS_OFF) + b * T + (tid & 7) * 4);
    #pragma unroll
    for (int rr = 0; rr < 4; ++rr) {
        const size_t row = r0 + rr;
        float4 s1v = *(const float4*)((ws + P1_OFF) + row * T + (tid & 7) * 4);
        float4 s;
        s.x = s1v.x + psv.x; s.y = s1v.y + psv.y;
        s.z = s1v.z + psv.z; s.w = s1v.w + psv.w;
        float4* ov = (float4*)out + row * (S * T / 4);
        #pragma unroll
        for (int k = tid; k < S * T / 4; k += 256) {
            float4 v = p2v[k];
            float4 r;
            r.x = v.x + s.x; r.y = v.y + s.y; r.z = v.z + s.z; r.w = v.w + s.w;
            ov[k] = r;
        }
    }
}

extern "C" void kernel_launch(void* const* d_in, const int* in_sizes, int n_in,
                              void* d_out, int out_size, void* d_ws, size_t ws_size,
                              hipStream_t stream)
{
    const float* seq  = (const float*)d_in[0];   // (16,1024)
    const float* E    = (const float*)d_in[1];   // (16,256,1024)
    const float* W    = (const float*)d_in[2];   // (32,3072)
    const float* bias = (const float*)d_in[3];   // (32,)
    float* out = (float*)d_out;                  // (16,256,256,32) f32
    float* ws  = (float*)d_ws;                   // ~1.05 MB + 64 B flags

    // Re-arm per-batch flags every launch. FIX vs R15: byte-correct address
    // ((char*)base + CNT_OFF floats * 4 bytes), not float-ptr + byte-count.
    hipMemsetAsync((void*)((char*)d_ws + (size_t)CNT_OFF * sizeof(float)), 0,
                   16 * sizeof(unsigned), stream);
    fused<<<1024, 256, 0, stream>>>(seq, E, W, bias, ws, out);
}

// Round 17
// 44.628 us; speedup vs baseline: 2.8012x; 2.8012x over previous
//
#include <hip/hip_runtime.h>

#define BS 16
#define S  256
#define H  1024
#define T  32
#define KSPLIT 4
#define KCH 256             // k per gemm block
#define BM 32               // rows per gemm block

// ws layout (floats): pp[4][4096][64] | ps[512]
//   pp cols 0..31 = p1 partials, 32..63 = p2 partials. No final p1/p2 —
//   the bcast kernel reduces pp inline (its read BW is idle; write-bound).
#define PP_OFF 0
#define PP_SZ  (KSPLIT * BS * S * 64)           // 1048576 floats
#define SLICE4 (PP_SZ / KSPLIT / 4)             // float4 per k-slice = 65536
#define PS_OFF (PP_OFF + PP_SZ)

typedef __bf16 bf16x8 __attribute__((ext_vector_type(8)));
typedef float  f32x4  __attribute__((ext_vector_type(4)));

__device__ inline bf16x8 to_bf8(float4 lo, float4 hi) {
    bf16x8 r;
    r[0] = (__bf16)lo.x; r[1] = (__bf16)lo.y; r[2] = (__bf16)lo.z; r[3] = (__bf16)lo.w;
    r[4] = (__bf16)hi.x; r[5] = (__bf16)hi.y; r[6] = (__bf16)hi.z; r[7] = (__bf16)hi.w;
    return r;
}

// ---------------------------------------------------------------------------
// Kernel A — byte-identical to R10's proven gemm_ps (640 blocks):
//   blk < 128 : ps — one wave per (b,t), coalesced + shfl_xor reduce.
//   blk >= 128: GEMM partials. g=blk-128: ks=g>>7 (k-chunk of 256),
//     m-tile=32 rows; wave w owns cols [16w,16w+16). E staged as bf16.
// ---------------------------------------------------------------------------
__global__ __launch_bounds__(256) void gemm_ps(
    const float* __restrict__ seq, const float* __restrict__ E,
    const float* __restrict__ W, const float* __restrict__ bias,
    float* __restrict__ ws)
{
    const int tid = threadIdx.x;
    const int lane = tid & 63, wv = tid >> 6;

    if (blockIdx.x < 128) {
        float* ps = ws + PS_OFF;
        const int o = blockIdx.x * 4 + wv;            // 0..511
        const int bb = o >> 5, t = o & 31;
        const float4* sp = (const float4*)(seq + (size_t)bb * H) + lane * 4;
        const float4* wp = (const float4*)(W + (size_t)t * (3 * H) + 2 * H) + lane * 4;
        float acc = 0.f;
        #pragma unroll
        for (int k = 0; k < 4; ++k) {
            float4 a = sp[k], w = wp[k];
            acc += a.x * w.x + a.y * w.y + a.z * w.z + a.w * w.w;
        }
        #pragma unroll
        for (int m = 32; m >= 1; m >>= 1) acc += __shfl_xor(acc, m);
        if (lane == 0) ps[o] = acc + bias[t];
        return;
    }

    __shared__ __align__(16) __bf16 Ebf[BM][280];     // 17.5 KB

    const int g = blockIdx.x - 128;
    const int ks = g >> 7;
    const int m0 = (g & 127) * BM;
    const int kbeg = ks * KCH;

    const int nb = wv * 16;
    const int wrow = nb + (lane & 15);                // output col 0..63
    const int ksub = (lane >> 4) * 8;                 // k sub-offset 0/8/16/24
    const float* wbase = W + (size_t)(wrow & 31) * (3 * H)
                           + ((wrow >> 5) ? H : 0) + kbeg + ksub;
    bf16x8 bfrag[8];
    #pragma unroll
    for (int s = 0; s < 8; ++s)
        bfrag[s] = to_bf8(*(const float4*)(wbase + s * 32),
                          *(const float4*)(wbase + s * 32 + 4));

    #pragma unroll
    for (int i = 0; i < 4; ++i) {
        int f = tid + i * 256;                        // 0..1023
        int row = f >> 5, c8 = f & 31;
        const float4* src = (const float4*)(E + (size_t)(m0 + row) * H
                                            + kbeg + c8 * 8);
        *(bf16x8*)&Ebf[row][c8 * 8] = to_bf8(src[0], src[1]);
    }
    __syncthreads();

    f32x4 acc0 = {0.f,0.f,0.f,0.f}, acc1 = {0.f,0.f,0.f,0.f};
    const int erow = lane & 15;
    #pragma unroll
    for (int s = 0; s < 8; ++s) {
        bf16x8 a0 = *(const bf16x8*)&Ebf[erow][s * 32 + ksub];
        bf16x8 a1 = *(const bf16x8*)&Ebf[erow + 16][s * 32 + ksub];
        acc0 = __builtin_amdgcn_mfma_f32_16x16x32_bf16(a0, bfrag[s], acc0, 0, 0, 0);
        acc1 = __builtin_amdgcn_mfma_f32_16x16x32_bf16(a1, bfrag[s], acc1, 0, 0, 0);
    }

    float* pp = ws + PP_OFF + (size_t)ks * (BS * S * 64);
    const int orow = (lane >> 4) * 4;
    const int ocol = nb + (lane & 15);
    #pragma unroll
    for (int r = 0; r < 4; ++r) {
        pp[(size_t)(m0 + orow + r) * 64 + ocol]      = acc0[r];
        pp[(size_t)(m0 + 16 + orow + r) * 64 + ocol] = acc1[r];
    }
}

// ---------------------------------------------------------------------------
// Kernel B — bcast with INLINE reduce (replaces reduce_p + bcast_add):
//   out[b,i,j,t] = Σks pp[ks][b*S+i][t] + ps[b,t] + Σks pp[ks][b*S+j][32+t]
//   The 4 p2-partial reads are L2-resident and hide under the write stream
//   (bcast was write-bound with idle read BW). No LDS, no barrier.
// ---------------------------------------------------------------------------
__global__ __launch_bounds__(256) void bcast_reduce(
    const float* __restrict__ ws, float* __restrict__ out)
{
    const int blk = blockIdx.x;                       // 0..4095 = b*S + i
    const int b = blk >> 8;
    const int tid = threadIdx.x;
    const int t4 = tid & 7;                           // float4 index within T

    const float4* pp = (const float4*)(ws + PP_OFF);  // [4][4096][16] float4/row

    // s[t] = Σks pp[ks][blk][t] + ps[b][t]  (this thread's 4 t-values)
    float4 s = *(const float4*)((ws + PS_OFF) + b * T + t4 * 4);
    #pragma unroll
    for (int ks = 0; ks < KSPLIT; ++ks) {
        float4 u = pp[(size_t)ks * SLICE4 + (size_t)blk * 16 + t4];
        s.x += u.x; s.y += u.y; s.z += u.z; s.w += u.w;
    }

    const size_t rowbase = (size_t)b * S * 16;        // float4 base of batch rows
    float4* ov = (float4*)out + (size_t)blk * (S * T / 4);

    #pragma unroll
    for (int k = tid; k < S * T / 4; k += 256) {      // k&7 == t4 always
        const size_t off = rowbase + (size_t)(k >> 3) * 16 + 8 + t4;
        float4 v0 = pp[0 * SLICE4 + off];
        float4 v1 = pp[1 * SLICE4 + off];
        float4 v2 = pp[2 * SLICE4 + off];
        float4 v3 = pp[3 * SLICE4 + off];
        float4 r;
        r.x = ((v0.x + v1.x) + (v2.x + v3.x)) + s.x;
        r.y = ((v0.y + v1.y) + (v2.y + v3.y)) + s.y;
        r.z = ((v0.z + v1.z) + (v2.z + v3.z)) + s.z;
        r.w = ((v0.w + v1.w) + (v2.w + v3.w)) + s.w;
        ov[k] = r;
    }
}

extern "C" void kernel_launch(void* const* d_in, const int* in_sizes, int n_in,
                              void* d_out, int out_size, void* d_ws, size_t ws_size,
                              hipStream_t stream)
{
    const float* seq  = (const float*)d_in[0];   // (16,1024)
    const float* E    = (const float*)d_in[1];   // (16,256,1024)
    const float* W    = (const float*)d_in[2];   // (32,3072)
    const float* bias = (const float*)d_in[3];   // (32,)
    float* out = (float*)d_out;                  // (16,256,256,32) f32
    float* ws  = (float*)d_ws;                   // ~4.2 MB used

    gemm_ps<<<640, 256, 0, stream>>>(seq, E, W, bias, ws);
    bcast_reduce<<<BS * S, 256, 0, stream>>>(ws, out);
}